// Round 7
// baseline (623.346 us; speedup 1.0000x reference)
//
#include <hip/hip_runtime.h>
#include <hip/hip_cooperative_groups.h>
#include <stdint.h>

namespace cg = cooperative_groups;

// SelfAttention: B=4, S=2048, D=1024, causal, single head of dim 1024.
// Inputs/outputs fp32; GEMMs run bf16 MFMA with fp32 accumulation.
// R7: one cooperative megakernel (qkv -> scores -> softmax -> pv with
// grid.sync between phases, shared 32KB LDS, 512 blocks = 2/CU) to kill
// launch gaps; R6's under-concurrent scores tiling and pv atomics reverted.

typedef unsigned short u16;
typedef __attribute__((ext_vector_type(8))) short shortx8;  // 8 bf16 (4 VGPRs)
typedef __attribute__((ext_vector_type(4))) float floatx4;

static constexpr int BB = 4;
static constexpr int SS = 2048;
static constexpr int DD = 1024;
static constexpr int NBLK = 512;  // coop grid: 2 blocks/CU on 256 CUs

__device__ __forceinline__ u16 f2bf(float f) {
  union { float f; uint32_t u; } c; c.f = f;
  uint32_t u = c.u;
  return (u16)((u + 0x7fffu + ((u >> 16) & 1u)) >> 16);  // RNE
}
__device__ __forceinline__ float bfhi2f(uint32_t u) {
  union { uint32_t u; float f; } c; c.u = u & 0xffff0000u; return c.f;
}
__device__ __forceinline__ float bflo2f(uint32_t u) {
  union { uint32_t u; float f; } c; c.u = u << 16; return c.f;
}

#define GLOAD_LDS16(g, l)                                                              \
  __builtin_amdgcn_global_load_lds((const __attribute__((address_space(1))) void*)(g), \
                                   (__attribute__((address_space(3))) void*)(l), 16, 0, 0)

// 128x128 C-tile GEMM core, BK=64, XOR-swizzled LDS (R5: zero bank conflicts).
// LDS buffers passed in so all phases of the megakernel share one 32KB pair.
__device__ __forceinline__ void gemm_core_128(
    const u16* __restrict__ A, const u16* __restrict__ Bt,
    int lda, int ldb, int m0, int n0, int kend, floatx4 acc[4][4],
    u16* lA, u16* lB)
{
  const int t = threadIdx.x;
  const int w = t >> 6, l = t & 63;
  const int wm = w >> 1, wn = w & 1;
  const int sr = l >> 3;
  const int scq = ((l & 7) ^ (l >> 3)) * 8;   // swizzled SOURCE chunk (elems)

#pragma unroll
  for (int i = 0; i < 4; ++i)
#pragma unroll
    for (int j = 0; j < 4; ++j)
      acc[i][j] = (floatx4){0.f, 0.f, 0.f, 0.f};

  const u16* Ab = A + (size_t)m0 * lda;
  const u16* Bb = Bt + (size_t)n0 * ldb;

  for (int k0 = 0; k0 < kend; k0 += 64) {
#pragma unroll
    for (int i = 0; i < 4; ++i) {
      const int row = w * 32 + i * 8;
      GLOAD_LDS16(Ab + (size_t)(row + sr) * lda + k0 + scq, &lA[row * 64]);
      GLOAD_LDS16(Bb + (size_t)(row + sr) * ldb + k0 + scq, &lB[row * 64]);
    }
    __syncthreads();

#pragma unroll
    for (int ks = 0; ks < 2; ++ks) {
      const int ca = ((ks * 4 + (l >> 4)) ^ (l & 7)) * 8;
      shortx8 af[4], bf[4];
#pragma unroll
      for (int i = 0; i < 4; ++i)
        af[i] = *(const shortx8*)&lA[(wm * 64 + i * 16 + (l & 15)) * 64 + ca];
#pragma unroll
      for (int i = 0; i < 4; ++i)
        bf[i] = *(const shortx8*)&lB[(wn * 64 + i * 16 + (l & 15)) * 64 + ca];
#pragma unroll
      for (int i = 0; i < 4; ++i)
#pragma unroll
        for (int j = 0; j < 4; ++j)
          acc[i][j] = __builtin_amdgcn_mfma_f32_16x16x32_bf16(af[i], bf[j], acc[i][j], 0, 0, 0);
    }
    __syncthreads();
  }
}

// ---------------- phases (shared by megakernel and fallback kernels) --------

__device__ __forceinline__ void phase_qkv(int bid, const u16* xb, const u16* Wt,
                                          u16* Q, u16* K, u16* Vt,
                                          u16* lA, u16* lB) {
  const int t = threadIdx.x, w = t >> 6, l = t & 63;
  const int wm = w >> 1, wn = w & 1;
  for (int tid = bid; tid < 1536; tid += NBLK) {  // 3 full rounds
    const int m0 = (tid & 63) * 128;
    const int n0t = (tid >> 6) * 128;
    floatx4 acc[4][4];
    gemm_core_128(xb, Wt, DD, DD, m0, n0t, DD, acc, lA, lB);

    if (n0t >= 2048) {  // V tile: write transposed into Vt[b][d][s]
      const int bb = m0 >> 11;
      const int s0 = (m0 & 2047) + wm * 64 + (l >> 4) * 4;
      u16* vt = Vt + (size_t)bb * DD * SS;
#pragma unroll
      for (int i = 0; i < 4; ++i)
#pragma unroll
        for (int j = 0; j < 4; ++j) {
          const int n = (n0t - 2048) + wn * 64 + j * 16 + (l & 15);
          const int s = s0 + i * 16;
          ushort4 o4;
          o4.x = f2bf(acc[i][j][0]);
          o4.y = f2bf(acc[i][j][1]);
          o4.z = f2bf(acc[i][j][2]);
          o4.w = f2bf(acc[i][j][3]);
          *(ushort4*)(vt + (size_t)n * SS + s) = o4;
        }
      continue;
    }

    u16* out = (n0t < 1024) ? Q : K;
    const int n0 = n0t & 1023;
#pragma unroll
    for (int i = 0; i < 4; ++i)
#pragma unroll
      for (int j = 0; j < 4; ++j)
#pragma unroll
        for (int r = 0; r < 4; ++r) {
          const int m = m0 + wm * 64 + i * 16 + (l >> 4) * 4 + r;
          const int n = n0 + wn * 64 + j * 16 + (l & 15);
          out[(size_t)m * DD + n] = f2bf(acc[i][j][r]);
        }
  }
}

__device__ __forceinline__ void phase_scores(int bid, const u16* Q, const u16* Kt,
                                             u16* Scb, u16* lA, u16* lB) {
  const int t = threadIdx.x, w = t >> 6, l = t & 63;
  const int wm = w >> 1, wn = w & 1;
  for (int tt = bid; tt < 544; tt += NBLK) {  // 4 batches x 136 tri-tiles
    const int b = tt / 136;
    const int tcode = tt - b * 136;
    int mb = (int)((sqrtf(8.0f * (float)tcode + 1.0f) - 1.0f) * 0.5f);
    while ((mb + 1) * (mb + 2) / 2 <= tcode) ++mb;
    while (mb * (mb + 1) / 2 > tcode) --mb;
    const int nb = tcode - mb * (mb + 1) / 2;
    const int m0 = mb * 128, n0 = nb * 128;

    floatx4 acc[4][4];
    gemm_core_128(Q + (size_t)b * SS * DD, Kt + (size_t)b * SS * DD,
                  DD, DD, m0, n0, DD, acc, lA, lB);

    u16* out = Scb + (size_t)b * SS * SS;
#pragma unroll
    for (int i = 0; i < 4; ++i)
#pragma unroll
      for (int j = 0; j < 4; ++j)
#pragma unroll
        for (int r = 0; r < 4; ++r) {
          const int m = m0 + wm * 64 + i * 16 + (l >> 4) * 4 + r;
          const int n = n0 + wn * 64 + j * 16 + (l & 15);
          out[(size_t)m * SS + n] = f2bf(acc[i][j][r] * 0.03125f);  // 1/sqrt(1024)
        }
  }
}

__device__ __forceinline__ void phase_softmax(int bid, const u16* Scb, u16* P) {
  const int wid = bid * 4 + (threadIdx.x >> 6);  // 0..2047
  const int l = threadIdx.x & 63;
  for (int rep = 0; rep < 4; ++rep) {
    const int row = wid + rep * 2048;  // b*2048 + i
    const int b = row >> 11, i = row & 2047;
    const u16* s = Scb + (size_t)b * SS * SS + (size_t)i * SS;
    u16* p = P + (size_t)b * SS * SS + (size_t)i * SS;
    const int n = i + 1;
    const int jend = (i + 128) & ~127;
    const int nc = (jend + 511) >> 9;

    float v[4][8];
    float mx = -INFINITY;
#pragma unroll
    for (int c = 0; c < 4; ++c) {
      if (c < nc) {
        const int col = c * 512 + l * 8;
        uint4 raw = *(const uint4*)(s + col);
        v[c][0] = bflo2f(raw.x); v[c][1] = bfhi2f(raw.x);
        v[c][2] = bflo2f(raw.y); v[c][3] = bfhi2f(raw.y);
        v[c][4] = bflo2f(raw.z); v[c][5] = bfhi2f(raw.z);
        v[c][6] = bflo2f(raw.w); v[c][7] = bfhi2f(raw.w);
#pragma unroll
        for (int e = 0; e < 8; ++e) {
          v[c][e] = (col + e < n) ? v[c][e] : -INFINITY;
          mx = fmaxf(mx, v[c][e]);
        }
      }
    }
#pragma unroll
    for (int o = 32; o > 0; o >>= 1) mx = fmaxf(mx, __shfl_xor(mx, o, 64));

    float sum = 0.f;
#pragma unroll
    for (int c = 0; c < 4; ++c) {
      if (c < nc) {
#pragma unroll
        for (int e = 0; e < 8; ++e) {
          v[c][e] = __expf(v[c][e] - mx);
          sum += v[c][e];
        }
      }
    }
#pragma unroll
    for (int o = 32; o > 0; o >>= 1) sum += __shfl_xor(sum, o, 64);
    const float inv = 1.0f / sum;

#pragma unroll
    for (int c = 0; c < 4; ++c) {
      if (c < nc) {
        const int col = c * 512 + l * 8;
        if (col < jend) {
          uint4 o4;
          o4.x = (uint32_t)f2bf(v[c][0] * inv) | ((uint32_t)f2bf(v[c][1] * inv) << 16);
          o4.y = (uint32_t)f2bf(v[c][2] * inv) | ((uint32_t)f2bf(v[c][3] * inv) << 16);
          o4.z = (uint32_t)f2bf(v[c][4] * inv) | ((uint32_t)f2bf(v[c][5] * inv) << 16);
          o4.w = (uint32_t)f2bf(v[c][6] * inv) | ((uint32_t)f2bf(v[c][7] * inv) << 16);
          *(uint4*)(p + col) = o4;
        }
      }
    }
  }
}

__device__ __forceinline__ void phase_pv(int bid, const u16* P, const u16* Vt,
                                         float* out, u16* lA, u16* lB) {
  const int b = bid >> 7;            // 512 tiles = 4 batches x (16 mb x 8 n)
  const int r = bid & 127;
  const int mb = r >> 3, n0 = (r & 7) * 128;
  const int m0 = mb * 128;
  floatx4 acc[4][4];
  gemm_core_128(P + (size_t)b * SS * SS, Vt + (size_t)b * DD * SS,
                SS, SS, m0, n0, m0 + 128, acc, lA, lB);

  float* o = out + (size_t)b * SS * DD;
  const int t = threadIdx.x, w = t >> 6, l = t & 63;
  const int wm = w >> 1, wn = w & 1;
#pragma unroll
  for (int i = 0; i < 4; ++i)
#pragma unroll
    for (int j = 0; j < 4; ++j)
#pragma unroll
      for (int r2 = 0; r2 < 4; ++r2) {
        const int m = m0 + wm * 64 + i * 16 + (l >> 4) * 4 + r2;
        const int n = n0 + wn * 64 + j * 16 + (l & 15);
        o[(size_t)m * DD + n] = acc[i][j][r2];
      }
}

// ---------------- megakernel (cooperative) ----------------------------------
__global__ __launch_bounds__(256, 2) void mega(const u16* xb, const u16* Wt,
                                               u16* Q, u16* K, u16* Vt,
                                               u16* Scb, u16* P, float* out) {
  __shared__ u16 lA[128 * 64];
  __shared__ u16 lB[128 * 64];
  cg::grid_group g = cg::this_grid();
  const int bid = blockIdx.x;
  phase_qkv(bid, xb, Wt, Q, K, Vt, lA, lB);
  __threadfence();
  g.sync();
  phase_scores(bid, Q, K, Scb, lA, lB);
  __threadfence();
  g.sync();
  phase_softmax(bid, Scb, P);
  __threadfence();
  g.sync();
  phase_pv(bid, P, Vt, out, lA, lB);
}

// ---------------- fallback (non-cooperative) kernels -------------------------
__global__ __launch_bounds__(256, 2) void qkv_k(const u16* xb, const u16* Wt,
                                                u16* Q, u16* K, u16* Vt) {
  __shared__ u16 lA[128 * 64];
  __shared__ u16 lB[128 * 64];
  phase_qkv(blockIdx.x, xb, Wt, Q, K, Vt, lA, lB);
}
__global__ __launch_bounds__(256, 2) void scores_k(const u16* Q, const u16* Kt,
                                                   u16* Scb) {
  __shared__ u16 lA[128 * 64];
  __shared__ u16 lB[128 * 64];
  phase_scores(blockIdx.x, Q, Kt, Scb, lA, lB);
}
__global__ __launch_bounds__(256) void softmax_k(const u16* Scb, u16* P) {
  phase_softmax(blockIdx.x, Scb, P);
}
__global__ __launch_bounds__(256, 2) void pv_k(const u16* P, const u16* Vt,
                                               float* out) {
  __shared__ u16 lA[128 * 64];
  __shared__ u16 lB[128 * 64];
  phase_pv(blockIdx.x, P, Vt, out, lA, lB);
}

// ---------------- prep: x fp32->bf16 + W transpose+convert -------------------
__global__ __launch_bounds__(256) void prep(const float* __restrict__ x,
                                            const float* __restrict__ WQ,
                                            const float* __restrict__ WK,
                                            const float* __restrict__ WV,
                                            u16* __restrict__ xb,
                                            u16* __restrict__ Wt) {
  __shared__ float tile[64][65];
  const int bid = blockIdx.x;
  const int t = threadIdx.x;
  if (bid < 8192) {
    const size_t i = (size_t)bid * 256 + t;
    float4 v = ((const float4*)x)[i];
    ushort4 o;
    o.x = f2bf(v.x); o.y = f2bf(v.y); o.z = f2bf(v.z); o.w = f2bf(v.w);
    ((ushort4*)xb)[i] = o;
    return;
  }
  const int r = bid - 8192;
  const int wsel = r >> 8;
  const int rr = r & 255;
  const int k0 = (rr >> 4) * 64, n0 = (rr & 15) * 64;
  const float* W = wsel == 0 ? WQ : (wsel == 1 ? WK : WV);
  const int tx = t & 63, ty = t >> 6;
#pragma unroll
  for (int i = 0; i < 16; ++i)
    tile[ty + i * 4][tx] = W[(size_t)(k0 + ty + i * 4) * DD + n0 + tx];
  __syncthreads();
  u16* dst = Wt + (size_t)wsel * DD * DD;
#pragma unroll
  for (int i = 0; i < 16; ++i)
    dst[(size_t)(n0 + ty + i * 4) * DD + k0 + tx] = f2bf(tile[tx][ty + i * 4]);
}

extern "C" void kernel_launch(void* const* d_in, const int* in_sizes, int n_in,
                              void* d_out, int out_size, void* d_ws, size_t ws_size,
                              hipStream_t stream) {
  const float* x  = (const float*)d_in[0];
  const float* WQ = (const float*)d_in[1];
  const float* WK = (const float*)d_in[2];
  const float* WV = (const float*)d_in[3];
  float* out = (float*)d_out;

  // workspace carve (bytes): Wt 6M | xb 16M | Q 16M | K 16M | Vt 16M | P 32M | Scb 32M
  char* ws = (char*)d_ws;
  const size_t WT_OFF = 0;
  const size_t XB_OFF = WT_OFF + (size_t)3072 * 1024 * 2;
  const size_t Q_OFF  = XB_OFF + (size_t)BB * SS * DD * 2;
  const size_t K_OFF  = Q_OFF + (size_t)BB * SS * DD * 2;
  const size_t VT_OFF = K_OFF + (size_t)BB * SS * DD * 2;
  const size_t P_OFF  = VT_OFF + (size_t)BB * SS * DD * 2;
  const size_t SC_OFF = P_OFF + (size_t)BB * SS * SS * 2;
  u16* Wt  = (u16*)(ws + WT_OFF);
  u16* xb  = (u16*)(ws + XB_OFF);
  u16* Q   = (u16*)(ws + Q_OFF);
  u16* Kb  = (u16*)(ws + K_OFF);
  u16* Vt  = (u16*)(ws + VT_OFF);
  u16* P   = (u16*)(ws + P_OFF);
  u16* Scb = (u16*)(ws + SC_OFF);

  hipLaunchKernelGGL(prep, dim3(8960), dim3(256), 0, stream, x, WQ, WK, WV, xb, Wt);

  void* args[8] = {(void*)&xb, (void*)&Wt, (void*)&Q, (void*)&Kb,
                   (void*)&Vt, (void*)&Scb, (void*)&P, (void*)&out};
  hipError_t e = hipLaunchCooperativeKernel((void*)mega, dim3(NBLK), dim3(256),
                                            args, 0, stream);
  if (e != hipSuccess) {
    // fallback: same phases as separate (non-cooperative) launches
    hipLaunchKernelGGL(qkv_k, dim3(NBLK), dim3(256), 0, stream, xb, Wt, Q, Kb, Vt);
    hipLaunchKernelGGL(scores_k, dim3(NBLK), dim3(256), 0, stream, Q, Kb, Scb);
    hipLaunchKernelGGL(softmax_k, dim3(NBLK), dim3(256), 0, stream, Scb, P);
    hipLaunchKernelGGL(pv_k, dim3(NBLK), dim3(256), 0, stream, P, Vt, out);
  }
}

// Round 8
// 556.833 us; speedup vs baseline: 1.1194x; 1.1194x over previous
//
#include <hip/hip_runtime.h>
#include <stdint.h>

// SelfAttention: B=4, S=2048, D=1024, causal, single head of dim 1024.
// Inputs/outputs fp32; GEMMs run bf16 MFMA with fp32 accumulation.
// R8: single cooperative megakernel (prep->qkv->scores->softmax->pv) with a
// CUSTOM tree grid-barrier (cg::grid sync measured ~120us/sync in R7 — the
// whole R7 regression). Barriers are single-use, pre-zeroed via memset.

typedef unsigned short u16;
typedef __attribute__((ext_vector_type(8))) short shortx8;  // 8 bf16 (4 VGPRs)
typedef __attribute__((ext_vector_type(4))) float floatx4;

static constexpr int BB = 4;
static constexpr int SS = 2048;
static constexpr int DD = 1024;
static constexpr int NBLK = 512;          // 2 blocks/CU on 256 CUs
static constexpr int BAR_INTS = 1280;     // per-barrier stride (ints)
static constexpr int BAR_BYTES = 4 * BAR_INTS * 4;  // 4 barriers

__device__ __forceinline__ u16 f2bf(float f) {
  union { float f; uint32_t u; } c; c.f = f;
  uint32_t u = c.u;
  return (u16)((u + 0x7fffu + ((u >> 16) & 1u)) >> 16);  // RNE
}
__device__ __forceinline__ float bfhi2f(uint32_t u) {
  union { uint32_t u; float f; } c; c.u = u & 0xffff0000u; return c.f;
}
__device__ __forceinline__ float bflo2f(uint32_t u) {
  union { uint32_t u; float f; } c; c.u = u << 16; return c.f;
}

#define GLOAD_LDS16(g, l)                                                              \
  __builtin_amdgcn_global_load_lds((const __attribute__((address_space(1))) void*)(g), \
                                   (__attribute__((address_space(3))) void*)(l), 16, 0, 0)

// ---- custom single-use tree grid barrier --------------------------------
// layout (ints): [0]=gen flag, [16]=root ctr, [32+g*16] 64 group ctrs,
// [32+1024+s*16] 8 super ctrs. All pre-zeroed by hipMemsetAsync.
__device__ __forceinline__ void gridbar(int* bar, int bid) {
  __syncthreads();                        // all block stores issued & drained
  if (threadIdx.x == 0) {
    __threadfence();                      // flush this XCD's L2 (release)
    const int g = bid >> 3;               // 64 groups of 8 blocks
    if (atomicAdd(bar + 32 + g * 16, 1) == 7) {
      const int s = g >> 3;               // 8 supers of 8 groups
      if (atomicAdd(bar + 32 + 1024 + s * 16, 1) == 7) {
        if (atomicAdd(bar + 16, 1) == 7) {
          __hip_atomic_store(bar, 1, __ATOMIC_RELEASE, __HIP_MEMORY_SCOPE_AGENT);
        }
      }
    }
    while (__hip_atomic_load(bar, __ATOMIC_ACQUIRE, __HIP_MEMORY_SCOPE_AGENT) == 0)
      __builtin_amdgcn_s_sleep(8);
    __threadfence();                      // invalidate caches (acquire)
  }
  __syncthreads();
}

// 128x128 C-tile GEMM core, BK=64, XOR-swizzled LDS (R5: zero bank conflicts).
// Static __shared__ (single instance, reused sequentially across phases).
__device__ __forceinline__ void gemm_core_128(
    const u16* __restrict__ A, const u16* __restrict__ Bt,
    int lda, int ldb, int m0, int n0, int kend, floatx4 acc[4][4])
{
  __shared__ u16 lA[128 * 64];
  __shared__ u16 lB[128 * 64];
  const int t = threadIdx.x;
  const int w = t >> 6, l = t & 63;
  const int wm = w >> 1, wn = w & 1;
  const int sr = l >> 3;
  const int scq = ((l & 7) ^ (l >> 3)) * 8;   // swizzled SOURCE chunk (elems)

#pragma unroll
  for (int i = 0; i < 4; ++i)
#pragma unroll
    for (int j = 0; j < 4; ++j)
      acc[i][j] = (floatx4){0.f, 0.f, 0.f, 0.f};

  const u16* Ab = A + (size_t)m0 * lda;
  const u16* Bb = Bt + (size_t)n0 * ldb;

  for (int k0 = 0; k0 < kend; k0 += 64) {
#pragma unroll
    for (int i = 0; i < 4; ++i) {
      const int row = w * 32 + i * 8;
      GLOAD_LDS16(Ab + (size_t)(row + sr) * lda + k0 + scq, &lA[row * 64]);
      GLOAD_LDS16(Bb + (size_t)(row + sr) * ldb + k0 + scq, &lB[row * 64]);
    }
    __syncthreads();

#pragma unroll
    for (int ks = 0; ks < 2; ++ks) {
      const int ca = ((ks * 4 + (l >> 4)) ^ (l & 7)) * 8;
      shortx8 af[4], bf[4];
#pragma unroll
      for (int i = 0; i < 4; ++i)
        af[i] = *(const shortx8*)&lA[(wm * 64 + i * 16 + (l & 15)) * 64 + ca];
#pragma unroll
      for (int i = 0; i < 4; ++i)
        bf[i] = *(const shortx8*)&lB[(wn * 64 + i * 16 + (l & 15)) * 64 + ca];
#pragma unroll
      for (int i = 0; i < 4; ++i)
#pragma unroll
        for (int j = 0; j < 4; ++j)
          acc[i][j] = __builtin_amdgcn_mfma_f32_16x16x32_bf16(af[i], bf[j], acc[i][j], 0, 0, 0);
    }
    __syncthreads();
  }
}

// ---------------- phases ----------------------------------------------------

// phase 0: xb = bf16(x) grid-stride; Wt[n][k] = bf16(W[k][n]) via LDS tiles.
__device__ __forceinline__ void phase_prep(int bid, const float* x,
                                           const float* WQ, const float* WK,
                                           const float* WV,
                                           u16* xb, u16* Wt) {
  __shared__ float tile[64][65];
  const int t = threadIdx.x;
  const int tid = bid * 256 + t;
  // x convert: 2,097,152 float4 over 131072 threads = 16 each
#pragma unroll
  for (int rep = 0; rep < 16; ++rep) {
    const size_t i = (size_t)rep * 131072 + tid;
    float4 v = ((const float4*)x)[i];
    ushort4 o;
    o.x = f2bf(v.x); o.y = f2bf(v.y); o.z = f2bf(v.z); o.w = f2bf(v.w);
    ((ushort4*)xb)[i] = o;
  }
  // W transpose: 768 64x64 tile-jobs over 512 blocks
  const int tx = t & 63, ty = t >> 6;
  for (int job = bid; job < 768; job += NBLK) {
    const int wsel = job >> 8;           // 0..2
    const int rr = job & 255;
    const int k0 = (rr >> 4) * 64, n0 = (rr & 15) * 64;
    const float* W = wsel == 0 ? WQ : (wsel == 1 ? WK : WV);
    __syncthreads();  // protect tile from previous job
#pragma unroll
    for (int i = 0; i < 16; ++i)
      tile[ty + i * 4][tx] = W[(size_t)(k0 + ty + i * 4) * DD + n0 + tx];
    __syncthreads();
    u16* dst = Wt + (size_t)wsel * DD * DD;
#pragma unroll
    for (int i = 0; i < 16; ++i)
      dst[(size_t)(n0 + ty + i * 4) * DD + k0 + tx] = f2bf(tile[tx][ty + i * 4]);
  }
}

__device__ __forceinline__ void phase_qkv(int bid, const u16* xb, const u16* Wt,
                                          u16* Q, u16* K, u16* Vt) {
  const int t = threadIdx.x, w = t >> 6, l = t & 63;
  const int wm = w >> 1, wn = w & 1;
  for (int tid = bid; tid < 1536; tid += NBLK) {  // 3 full rounds
    const int m0 = (tid & 63) * 128;
    const int n0t = (tid >> 6) * 128;
    floatx4 acc[4][4];
    gemm_core_128(xb, Wt, DD, DD, m0, n0t, DD, acc);

    if (n0t >= 2048) {  // V tile: write transposed into Vt[b][d][s]
      const int bb = m0 >> 11;
      const int s0 = (m0 & 2047) + wm * 64 + (l >> 4) * 4;
      u16* vt = Vt + (size_t)bb * DD * SS;
#pragma unroll
      for (int i = 0; i < 4; ++i)
#pragma unroll
        for (int j = 0; j < 4; ++j) {
          const int n = (n0t - 2048) + wn * 64 + j * 16 + (l & 15);
          const int s = s0 + i * 16;
          ushort4 o4;
          o4.x = f2bf(acc[i][j][0]);
          o4.y = f2bf(acc[i][j][1]);
          o4.z = f2bf(acc[i][j][2]);
          o4.w = f2bf(acc[i][j][3]);
          *(ushort4*)(vt + (size_t)n * SS + s) = o4;
        }
      continue;
    }

    u16* out = (n0t < 1024) ? Q : K;
    const int n0 = n0t & 1023;
#pragma unroll
    for (int i = 0; i < 4; ++i)
#pragma unroll
      for (int j = 0; j < 4; ++j)
#pragma unroll
        for (int r = 0; r < 4; ++r) {
          const int m = m0 + wm * 64 + i * 16 + (l >> 4) * 4 + r;
          const int n = n0 + wn * 64 + j * 16 + (l & 15);
          out[(size_t)m * DD + n] = f2bf(acc[i][j][r]);
        }
  }
}

__device__ __forceinline__ void phase_scores(int bid, const u16* Q, const u16* Kt,
                                             u16* Scb) {
  const int t = threadIdx.x, w = t >> 6, l = t & 63;
  const int wm = w >> 1, wn = w & 1;
  for (int tt = bid; tt < 544; tt += NBLK) {  // 4 batches x 136 tri-tiles
    const int b = tt / 136;
    const int tcode = tt - b * 136;
    int mb = (int)((sqrtf(8.0f * (float)tcode + 1.0f) - 1.0f) * 0.5f);
    while ((mb + 1) * (mb + 2) / 2 <= tcode) ++mb;
    while (mb * (mb + 1) / 2 > tcode) --mb;
    const int nb = tcode - mb * (mb + 1) / 2;
    const int m0 = mb * 128, n0 = nb * 128;

    floatx4 acc[4][4];
    gemm_core_128(Q + (size_t)b * SS * DD, Kt + (size_t)b * SS * DD,
                  DD, DD, m0, n0, DD, acc);

    u16* out = Scb + (size_t)b * SS * SS;
#pragma unroll
    for (int i = 0; i < 4; ++i)
#pragma unroll
      for (int j = 0; j < 4; ++j)
#pragma unroll
        for (int r = 0; r < 4; ++r) {
          const int m = m0 + wm * 64 + i * 16 + (l >> 4) * 4 + r;
          const int n = n0 + wn * 64 + j * 16 + (l & 15);
          out[(size_t)m * SS + n] = f2bf(acc[i][j][r] * 0.03125f);  // 1/sqrt(1024)
        }
  }
}

__device__ __forceinline__ void phase_softmax(int bid, const u16* Scb, u16* P) {
  const int wid = bid * 4 + (threadIdx.x >> 6);  // 0..2047
  const int l = threadIdx.x & 63;
  for (int rep = 0; rep < 4; ++rep) {
    const int row = wid + rep * 2048;  // b*2048 + i
    const int b = row >> 11, i = row & 2047;
    const u16* s = Scb + (size_t)b * SS * SS + (size_t)i * SS;
    u16* p = P + (size_t)b * SS * SS + (size_t)i * SS;
    const int n = i + 1;
    const int jend = (i + 128) & ~127;
    const int nc = (jend + 511) >> 9;

    float v[4][8];
    float mx = -INFINITY;
#pragma unroll
    for (int c = 0; c < 4; ++c) {
      if (c < nc) {
        const int col = c * 512 + l * 8;
        uint4 raw = *(const uint4*)(s + col);
        v[c][0] = bflo2f(raw.x); v[c][1] = bfhi2f(raw.x);
        v[c][2] = bflo2f(raw.y); v[c][3] = bfhi2f(raw.y);
        v[c][4] = bflo2f(raw.z); v[c][5] = bfhi2f(raw.z);
        v[c][6] = bflo2f(raw.w); v[c][7] = bfhi2f(raw.w);
#pragma unroll
        for (int e = 0; e < 8; ++e) {
          v[c][e] = (col + e < n) ? v[c][e] : -INFINITY;
          mx = fmaxf(mx, v[c][e]);
        }
      }
    }
#pragma unroll
    for (int o = 32; o > 0; o >>= 1) mx = fmaxf(mx, __shfl_xor(mx, o, 64));

    float sum = 0.f;
#pragma unroll
    for (int c = 0; c < 4; ++c) {
      if (c < nc) {
#pragma unroll
        for (int e = 0; e < 8; ++e) {
          v[c][e] = __expf(v[c][e] - mx);
          sum += v[c][e];
        }
      }
    }
#pragma unroll
    for (int o = 32; o > 0; o >>= 1) sum += __shfl_xor(sum, o, 64);
    const float inv = 1.0f / sum;

#pragma unroll
    for (int c = 0; c < 4; ++c) {
      if (c < nc) {
        const int col = c * 512 + l * 8;
        if (col < jend) {
          uint4 o4;
          o4.x = (uint32_t)f2bf(v[c][0] * inv) | ((uint32_t)f2bf(v[c][1] * inv) << 16);
          o4.y = (uint32_t)f2bf(v[c][2] * inv) | ((uint32_t)f2bf(v[c][3] * inv) << 16);
          o4.z = (uint32_t)f2bf(v[c][4] * inv) | ((uint32_t)f2bf(v[c][5] * inv) << 16);
          o4.w = (uint32_t)f2bf(v[c][6] * inv) | ((uint32_t)f2bf(v[c][7] * inv) << 16);
          *(uint4*)(p + col) = o4;
        }
      }
    }
  }
}

__device__ __forceinline__ void phase_pv(int bid, const u16* P, const u16* Vt,
                                         float* out) {
  const int b = bid >> 7;            // 512 tiles = 4 batches x (16 mb x 8 n)
  const int r = bid & 127;
  const int mb = r >> 3, n0 = (r & 7) * 128;
  const int m0 = mb * 128;
  floatx4 acc[4][4];
  gemm_core_128(P + (size_t)b * SS * SS, Vt + (size_t)b * DD * SS,
                SS, SS, m0, n0, m0 + 128, acc);

  float* o = out + (size_t)b * SS * DD;
  const int t = threadIdx.x, w = t >> 6, l = t & 63;
  const int wm = w >> 1, wn = w & 1;
#pragma unroll
  for (int i = 0; i < 4; ++i)
#pragma unroll
    for (int j = 0; j < 4; ++j)
#pragma unroll
      for (int r2 = 0; r2 < 4; ++r2) {
        const int m = m0 + wm * 64 + i * 16 + (l >> 4) * 4 + r2;
        const int n = n0 + wn * 64 + j * 16 + (l & 15);
        o[(size_t)m * DD + n] = acc[i][j][r2];
      }
}

// ---------------- megakernel (cooperative, custom barriers) ------------------
__global__ __launch_bounds__(256, 2) void mega(const float* x, const float* WQ,
                                               const float* WK, const float* WV,
                                               u16* xb, u16* Wt,
                                               u16* Q, u16* K, u16* Vt,
                                               u16* Scb, u16* P, float* out,
                                               int* bar) {
  const int bid = blockIdx.x;
  phase_prep(bid, x, WQ, WK, WV, xb, Wt);
  gridbar(bar + 0 * BAR_INTS, bid);
  phase_qkv(bid, xb, Wt, Q, K, Vt);
  gridbar(bar + 1 * BAR_INTS, bid);
  phase_scores(bid, Q, K, Scb);
  gridbar(bar + 2 * BAR_INTS, bid);
  phase_softmax(bid, Scb, P);
  gridbar(bar + 3 * BAR_INTS, bid);
  phase_pv(bid, P, Vt, out);
}

// ---------------- fallback (non-cooperative) kernels -------------------------
__global__ __launch_bounds__(256) void prep_k(const float* x, const float* WQ,
                                              const float* WK, const float* WV,
                                              u16* xb, u16* Wt) {
  phase_prep(blockIdx.x, x, WQ, WK, WV, xb, Wt);
}
__global__ __launch_bounds__(256, 2) void qkv_k(const u16* xb, const u16* Wt,
                                                u16* Q, u16* K, u16* Vt) {
  phase_qkv(blockIdx.x, xb, Wt, Q, K, Vt);
}
__global__ __launch_bounds__(256, 2) void scores_k(const u16* Q, const u16* Kt,
                                                   u16* Scb) {
  phase_scores(blockIdx.x, Q, Kt, Scb);
}
__global__ __launch_bounds__(256) void softmax_k(const u16* Scb, u16* P) {
  phase_softmax(blockIdx.x, Scb, P);
}
__global__ __launch_bounds__(256, 2) void pv_k(const u16* P, const u16* Vt,
                                               float* out) {
  phase_pv(blockIdx.x, P, Vt, out);
}

extern "C" void kernel_launch(void* const* d_in, const int* in_sizes, int n_in,
                              void* d_out, int out_size, void* d_ws, size_t ws_size,
                              hipStream_t stream) {
  const float* x  = (const float*)d_in[0];
  const float* WQ = (const float*)d_in[1];
  const float* WK = (const float*)d_in[2];
  const float* WV = (const float*)d_in[3];
  float* out = (float*)d_out;

  // workspace carve: Wt 6M | xb 16M | Q 16M | K 16M | Vt 16M | P 32M | Scb 32M | bar 20K
  char* ws = (char*)d_ws;
  const size_t WT_OFF  = 0;
  const size_t XB_OFF  = WT_OFF + (size_t)3072 * 1024 * 2;
  const size_t Q_OFF   = XB_OFF + (size_t)BB * SS * DD * 2;
  const size_t K_OFF   = Q_OFF + (size_t)BB * SS * DD * 2;
  const size_t VT_OFF  = K_OFF + (size_t)BB * SS * DD * 2;
  const size_t P_OFF   = VT_OFF + (size_t)BB * SS * DD * 2;
  const size_t SC_OFF  = P_OFF + (size_t)BB * SS * SS * 2;
  const size_t BAR_OFF = SC_OFF + (size_t)BB * SS * SS * 2;
  u16* Wt  = (u16*)(ws + WT_OFF);
  u16* xb  = (u16*)(ws + XB_OFF);
  u16* Q   = (u16*)(ws + Q_OFF);
  u16* Kb  = (u16*)(ws + K_OFF);
  u16* Vt  = (u16*)(ws + VT_OFF);
  u16* P   = (u16*)(ws + P_OFF);
  u16* Scb = (u16*)(ws + SC_OFF);
  int* bar = (int*)(ws + BAR_OFF);

  hipMemsetAsync(bar, 0, BAR_BYTES, stream);

  const float* x_ = x; const float* wq_ = WQ; const float* wk_ = WK; const float* wv_ = WV;
  void* args[13] = {(void*)&x_, (void*)&wq_, (void*)&wk_, (void*)&wv_,
                    (void*)&xb, (void*)&Wt, (void*)&Q, (void*)&Kb, (void*)&Vt,
                    (void*)&Scb, (void*)&P, (void*)&out, (void*)&bar};
  hipError_t e = hipLaunchCooperativeKernel((void*)mega, dim3(NBLK), dim3(256),
                                            args, 0, stream);
  if (e != hipSuccess) {
    hipLaunchKernelGGL(prep_k, dim3(NBLK), dim3(256), 0, stream, x, WQ, WK, WV, xb, Wt);
    hipLaunchKernelGGL(qkv_k, dim3(NBLK), dim3(256), 0, stream, xb, Wt, Q, Kb, Vt);
    hipLaunchKernelGGL(scores_k, dim3(NBLK), dim3(256), 0, stream, Q, Kb, Scb);
    hipLaunchKernelGGL(softmax_k, dim3(NBLK), dim3(256), 0, stream, Scb, P);
    hipLaunchKernelGGL(pv_k, dim3(NBLK), dim3(256), 0, stream, P, Vt, out);
  }
}